// Round 1
// baseline (126.879 us; speedup 1.0000x reference)
//
#include <hip/hip_runtime.h>
#include <math.h>

// HungarianMatcher cost matrix: C[n, t] = 5*L1(mid) + 2*focal_class + 5*(L1(head)+L1(tip))
// N = bs*nq = 28800 rows, T = 960 targets, nc = 2 classes.
// Write-BW bound: 110.6 MB out. Strategy: per-block row staging in LDS,
// per-thread target data in registers (reused across NB rows), float4 stores.

#define NB 16      // query rows per block
#define BLOCK 256

__global__ __launch_bounds__(BLOCK) void matcher_kernel(
    const float* __restrict__ logits,   // [N,2]
    const float* __restrict__ pscrews,  // [N,4]
    const int*   __restrict__ tlabels,  // [T]
    const float* __restrict__ tscrews,  // [T,4]
    float*       __restrict__ out,      // [N,T]
    int N, int T)
{
    __shared__ float row[NB][8];  // hx,hy,tx,ty, mx,my, cc0,cc1 (cc pre-scaled by 2)
    const int tid = threadIdx.x;
    const int n0  = blockIdx.x * NB;

    // ---- stage per-row (query) data: 1 thread per row ----
    if (tid < NB && (n0 + tid) < N) {
        const int n = n0 + tid;
        float4 s = reinterpret_cast<const float4*>(pscrews)[n];
        float hx = s.x, hy = s.y, tx = s.z, ty = s.w;
        row[tid][0] = hx; row[tid][1] = hy;
        row[tid][2] = tx; row[tid][3] = ty;
        row[tid][4] = (hx + tx) * 0.5f;
        row[tid][5] = (hy + ty) * 0.5f;
        float l0 = logits[n * 2 + 0];
        float l1 = logits[n * 2 + 1];
        #pragma unroll
        for (int c = 0; c < 2; ++c) {
            float l = (c == 0) ? l0 : l1;
            float p = 1.0f / (1.0f + expf(-l));
            float om = 1.0f - p;
            float pos = om * om * (-logf(p + 1e-8f));
            float neg = p * p * (-logf(1.0f - p + 1e-8f));
            row[tid][6 + c] = 2.0f * (pos - neg);  // pre-scale by COST_CLASS
        }
    }

    // ---- load this thread's 4 targets into registers (reused for all NB rows) ----
    const int chunk = tid;                 // target chunk: targets [4*chunk, 4*chunk+3]
    const bool active = (chunk * 4 + 3) < T;
    float thx[4], thy[4], ttx[4], tty[4], tmx[4], tmy[4];
    int   lab[4];
    if (active) {
        int4 lb = reinterpret_cast<const int4*>(tlabels)[chunk];
        lab[0] = lb.x; lab[1] = lb.y; lab[2] = lb.z; lab[3] = lb.w;
        #pragma unroll
        for (int j = 0; j < 4; ++j) {
            float4 s = reinterpret_cast<const float4*>(tscrews)[chunk * 4 + j];
            thx[j] = s.x; thy[j] = s.y; ttx[j] = s.z; tty[j] = s.w;
            tmx[j] = (s.x + s.z) * 0.5f;
            tmy[j] = (s.y + s.w) * 0.5f;
        }
    }

    __syncthreads();

    if (!active) return;

    for (int r = 0; r < NB; ++r) {
        const int n = n0 + r;
        if (n >= N) break;
        float4 a = *reinterpret_cast<const float4*>(&row[r][0]);  // hx,hy,tx,ty
        float4 b = *reinterpret_cast<const float4*>(&row[r][4]);  // mx,my,cc0,cc1
        float4 res;
        float v[4];
        #pragma unroll
        for (int j = 0; j < 4; ++j) {
            float d = fabsf(a.x - thx[j]) + fabsf(a.y - thy[j])
                    + fabsf(a.z - ttx[j]) + fabsf(a.w - tty[j])
                    + fabsf(b.x - tmx[j]) + fabsf(b.y - tmy[j]);
            float cc = (lab[j] != 0) ? b.w : b.z;
            v[j] = fmaf(d, 5.0f, cc);
        }
        res.x = v[0]; res.y = v[1]; res.z = v[2]; res.w = v[3];
        reinterpret_cast<float4*>(out)[(n * T) / 4 + chunk] = res;
    }
}

extern "C" void kernel_launch(void* const* d_in, const int* in_sizes, int n_in,
                              void* d_out, int out_size, void* d_ws, size_t ws_size,
                              hipStream_t stream) {
    const float* logits  = (const float*)d_in[0];   // [bs, nq, 2]
    const float* pscrews = (const float*)d_in[1];   // [bs, nq, 4]
    const int*   tlabels = (const int*)d_in[2];     // [T]
    const float* tscrews = (const float*)d_in[3];   // [T, 4]
    float* out = (float*)d_out;

    const int N = in_sizes[1] / 4;   // bs*nq
    const int T = in_sizes[2];       // total targets

    const int blocks = (N + NB - 1) / NB;
    matcher_kernel<<<blocks, BLOCK, 0, stream>>>(logits, pscrews, tlabels, tscrews, out, N, T);
}